// Round 21
// baseline (152.755 us; speedup 1.0000x reference)
//
#include <hip/hip_runtime.h>
#include <hip/hip_fp16.h>

typedef __attribute__((ext_vector_type(2)))  _Float16 half2v;  // 2 f16 = 1 VGPR
typedef __attribute__((ext_vector_type(8)))  _Float16 half8v;  // 8 f16 = 4 VGPR
typedef __attribute__((ext_vector_type(16))) float    f32x16;

// bswz step layout (512 f16 per step), offsets in steps:
//  L0 real [0,17)   L0 self [17,19)
//  L1 real [19,85)  L1 self [85,88)
//  L2 real [88,154) L2 self [154,157)
//  L3 real [157,223) L3 self [223,226)   (L3 steps now unused but kept: prep identical)
static constexpr int BSWZ_STEPS = 226;
static constexpr int BSWZ_TOT   = BSWZ_STEPS * 512;   // 115712 f16
static constexpr int W1H_TOT    = 4 * 160;

struct Prm {
    const float* x;
    const float* w1[4]; const float* b1[4];
    const float* w2[4]; const float* b2[4];
    const float* root[4]; const float* bias[4];
    _Float16* xin;    // N x 8 f16 (x[:,4:10], zero-padded)
    _Float16* bswz;
    _Float16* w1h;    // 640 f16
    _Float16* aggz;   // 3 * N * 32 f16 (agg0|agg1|agg2), zeroed here
    float* outz;      // N x 2 f32 (d_out), zeroed here
    int N;
};

// ---------------------------------------------------------------------------
// prep: identical to R19.
// ---------------------------------------------------------------------------
__global__ __launch_bounds__(256) void prep(Prm p, int NB8, int NZA, int NZO)
{
    int b = blockIdx.x;
    if (b < 452) {                                   // ---- bswz ----
        int i = b * 256 + threadIdx.x;
        int T = i >> 9, t2 = i & 511;
        int j = t2 & 7, l = (t2 >> 3) & 63;
        int g = l >> 5, o = l & 31;
        int layer, cls, t;
        if (T < 17)       { layer = 0; cls = 0; t = T; }
        else if (T < 19)  { layer = 0; cls = 1; t = T - 17; }
        else if (T < 85)  { layer = 1; cls = 0; t = T - 19; }
        else if (T < 88)  { layer = 1; cls = 1; t = T - 85; }
        else if (T < 154) { layer = 2; cls = 0; t = T - 88; }
        else if (T < 157) { layer = 2; cls = 1; t = T - 154; }
        else if (T < 223) { layer = 3; cls = 0; t = T - 157; }
        else              { layer = 3; cls = 1; t = T - 223; }
        const int INP   = (layer == 0) ? 8 : 32;
        const int IN_C  = (layer == 0) ? 6 : 32;
        const int OUT_C = (layer == 3) ? 2 : 32;
        float v = 0.f;
        if (cls == 0) {
            const int S_MAIN = 2 * INP;
            if (t < S_MAIN) {
                int kap = 16 * t + 8 * g + j;
                int k  = (INP == 8) ? (kap >> 3) : (kap >> 5);
                int ii = (INP == 8) ? (kap & 7)  : (kap & 31);
                if (ii < IN_C && o < OUT_C)
                    v = p.w2[layer][(size_t)k * (IN_C * OUT_C) + ii * OUT_C + o];
            } else {
                int ii = 16 * (t - S_MAIN) + 8 * g + j;
                if (ii < IN_C && o < OUT_C)
                    v = p.b2[layer][ii * OUT_C + o];
            }
        } else {
            const int nroot = (layer == 0) ? 1 : 2;
            if (t < nroot) {
                int ii = 16 * t + 8 * g + j;
                if (ii < IN_C && o < OUT_C)
                    v = p.root[layer][ii * OUT_C + o];
            } else {
                if (g == 0 && j == 0 && o < OUT_C)
                    v = p.bias[layer][o];
            }
        }
        p.bswz[i] = (_Float16)v;
    } else if (b < 452 + NB8) {                      // ---- pack xin ----
        int i = (b - 452) * 256 + threadIdx.x;
        if (i < p.N * 8) {
            int v = i >> 3, c = i & 7;
            float val = (c < 6) ? p.x[(size_t)v * 10 + 4 + c] : 0.f;
            p.xin[i] = (_Float16)val;
        }
    } else if (b < 452 + NB8 + NZA) {                // ---- zero agg0..2 ----
        long long i = (long long)(b - 452 - NB8) * 256 + threadIdx.x;
        if (i < (long long)p.N * 12)
            ((uint4*)p.aggz)[i] = uint4{0u, 0u, 0u, 0u};
    } else if (b < 452 + NB8 + NZA + NZO) {          // ---- zero out ----
        int v = (b - 452 - NB8 - NZA) * 256 + threadIdx.x;
        if (v < p.N)
            ((float2*)p.outz)[v] = float2{0.f, 0.f};
    } else {                                         // ---- w1h / b1h ----
        for (int i = threadIdx.x; i < W1H_TOT; i += 256) {
            int layer = i / 160, r = i % 160;
            float v = (r < 128) ? p.w1[layer][r]
                                : p.b1[layer][r - 128];
            p.w1h[i] = (_Float16)v;
        }
    }
}

// gather 32 f16 feats for node s, relu in packed f16
static __device__ __forceinline__ void gather32h(
    const _Float16* __restrict__ fprev, int s, int g, half8v& xh0, half8v& xh1)
{
    const half8v* fp = (const half8v*)(fprev + (size_t)s * 32);
    xh0 = fp[g];
    xh1 = fp[2 + g];
    #pragma unroll
    for (int j = 0; j < 8; ++j) {
        xh0[j] = xh0[j] > (_Float16)0.f ? xh0[j] : (_Float16)0.f;
        xh1[j] = xh1[j] > (_Float16)0.f ? xh1[j] : (_Float16)0.f;
    }
}

static __device__ __forceinline__ half8v splat8(_Float16 h)
{
    half8v r;
    #pragma unroll
    for (int j = 0; j < 8; ++j) r[j] = h;
    return r;
}

// paired pk-f16 atomic: lanes o and o^1 hold the same row, cols o / o^1.
static __device__ __forceinline__ void pk_atomic_row(
    _Float16* __restrict__ aggH, int row, int o, float mine)
{
    float oth = __shfl_xor(mine, 1);
    if ((o & 1) == 0 && row >= 0) {
        __half2 v = __floats2half2_rn(mine, oth);
        unsafeAtomicAdd((__half2*)aggH + (((size_t)row << 5) + o) / 2, v);
    }
}

// ---------------------------------------------------------------------------
// Edge kernel for layers 0-2: identical to R19's edge<INP,32>.
// ---------------------------------------------------------------------------
template<int INP>
__global__ __launch_bounds__(1024, 8) void edge(
    const _Float16* __restrict__ xin,
    const _Float16* __restrict__ fprev,
    const int*      __restrict__ src,
    const int*      __restrict__ dst,
    const float*    __restrict__ ea,
    const _Float16* __restrict__ w1h,
    const _Float16* __restrict__ bAll,
    _Float16* __restrict__ aggH,
    int E, int N, int ntileE, int ntot)
{
    constexpr int NREAL = (INP == 32) ? 66 : 17;
    constexpr int NSELF = (INP == 32) ? 3  : 2;
    constexpr int NSTEP = NREAL + NSELF;

    __shared__ half8v ldsb[NSTEP * 64];
    {
        const half8v* bp = (const half8v*)bAll;
        for (int i = threadIdx.x; i < NSTEP * 64; i += 1024)
            ldsb[i] = bp[i];
    }
    __syncthreads();

    const int lane = threadIdx.x & 63;
    const int g = lane >> 5, o = lane & 31;
    const int lrow = lane & 31;
    const int wv = (blockIdx.x * 1024 + threadIdx.x) >> 6;
    const int nw = gridDim.x * 16;

    const half2v* w1p = (const half2v*)w1h;
    const half2v* b1p = (const half2v*)(w1h + 128);
    const half2v zero2 = { (_Float16)0.f, (_Float16)0.f };

    half8v ones;
    #pragma unroll
    for (int j = 0; j < 8; ++j) ones[j] = (_Float16)0.f;
    ones[0] = (_Float16)1.f;

    for (int tile = wv; tile < ntot; tile += nw) {
        f32x16 C;
        #pragma unroll
        for (int i = 0; i < 16; ++i) C[i] = 0.f;

        if (tile < ntileE) {
            const int e0 = tile * 32;
            const int er = e0 + lrow;
            const int ec = er < E ? er : (E - 1);
            const int s  = src[ec];
            const float4 av = *(const float4*)(ea + 4ll * ec);
            half2v eax; eax[0] = (_Float16)av.x; eax[1] = eax[0];
            half2v eay; eay[0] = (_Float16)av.y; eay[1] = eay[0];
            half2v eaz; eaz[0] = (_Float16)av.z; eaz[1] = eaz[0];
            half2v eaw; eaw[0] = (_Float16)av.w; eaw[1] = eaw[0];

            half8v xh0, xh1;
            if constexpr (INP == 32) gather32h(fprev, s, g, xh0, xh1);
            else                     xh0 = *(const half8v*)(xin + (size_t)s * 8);

            if constexpr (INP == 32) {
                #pragma unroll 2
                for (int t = 0; t < 16; ++t) {
                    half2v h2 = eax * w1p[t] + b1p[t];
                    h2 = eay * w1p[16 + t] + h2;
                    h2 = eaz * w1p[32 + t] + h2;
                    h2 = eaw * w1p[48 + t] + h2;
                    h2 = __builtin_elementwise_max(h2, zero2);
                    half8v hsl = splat8(h2[0]);
                    half8v hsh = splat8(h2[1]);
                    half8v bf0 = ldsb[(4*t    ) * 64 + lane];
                    half8v bf1 = ldsb[(4*t + 1) * 64 + lane];
                    half8v bf2 = ldsb[(4*t + 2) * 64 + lane];
                    half8v bf3 = ldsb[(4*t + 3) * 64 + lane];
                    C = __builtin_amdgcn_mfma_f32_32x32x16_f16(hsl * xh0, bf0, C, 0, 0, 0);
                    C = __builtin_amdgcn_mfma_f32_32x32x16_f16(hsl * xh1, bf1, C, 0, 0, 0);
                    C = __builtin_amdgcn_mfma_f32_32x32x16_f16(hsh * xh0, bf2, C, 0, 0, 0);
                    C = __builtin_amdgcn_mfma_f32_32x32x16_f16(hsh * xh1, bf3, C, 0, 0, 0);
                }
                C = __builtin_amdgcn_mfma_f32_32x32x16_f16(xh0, ldsb[64*64 + lane], C, 0, 0, 0);
                C = __builtin_amdgcn_mfma_f32_32x32x16_f16(xh1, ldsb[65*64 + lane], C, 0, 0, 0);
            } else {
                #pragma unroll 4
                for (int t = 0; t < 16; ++t) {
                    half2v h2 = eax * w1p[t] + b1p[t];
                    h2 = eay * w1p[16 + t] + h2;
                    h2 = eaz * w1p[32 + t] + h2;
                    h2 = eaw * w1p[48 + t] + h2;
                    h2 = __builtin_elementwise_max(h2, zero2);
                    half8v hs = splat8(g ? h2[1] : h2[0]);
                    half8v bf = ldsb[t * 64 + lane];
                    C = __builtin_amdgcn_mfma_f32_32x32x16_f16(hs * xh0, bf, C, 0, 0, 0);
                }
                half8v zz;
                #pragma unroll
                for (int j = 0; j < 8; ++j) zz[j] = (_Float16)0.f;
                half8v a = (g == 0) ? xh0 : zz;
                C = __builtin_amdgcn_mfma_f32_32x32x16_f16(a, ldsb[16*64 + lane], C, 0, 0, 0);
            }

            #pragma unroll
            for (int q = 0; q < 4; ++q) {
                const int eb = e0 + 8 * q + 4 * g;
                int rows[4];
                if (eb + 3 < E) {
                    const int4 dd = *(const int4*)(dst + eb);
                    rows[0] = dd.x; rows[1] = dd.y; rows[2] = dd.z; rows[3] = dd.w;
                } else {
                    #pragma unroll
                    for (int m = 0; m < 4; ++m)
                        rows[m] = (eb + m < E) ? dst[eb + m] : -1;
                }
                #pragma unroll
                for (int m = 0; m < 4; ++m)
                    pk_atomic_row(aggH, rows[m], o, C[4*q + m]);
            }
        } else {
            const int v0 = (tile - ntileE) * 32;
            const int vr = v0 + lrow;
            const int vc = vr < N ? vr : (N - 1);

            if constexpr (INP == 32) {
                half8v xh0, xh1;
                gather32h(fprev, vc, g, xh0, xh1);
                C = __builtin_amdgcn_mfma_f32_32x32x16_f16(xh0,  ldsb[(NREAL+0)*64 + lane], C, 0, 0, 0);
                C = __builtin_amdgcn_mfma_f32_32x32x16_f16(xh1,  ldsb[(NREAL+1)*64 + lane], C, 0, 0, 0);
                C = __builtin_amdgcn_mfma_f32_32x32x16_f16(ones, ldsb[(NREAL+2)*64 + lane], C, 0, 0, 0);
            } else {
                half8v xh0 = *(const half8v*)(xin + (size_t)vc * 8);
                C = __builtin_amdgcn_mfma_f32_32x32x16_f16(xh0,  ldsb[(NREAL+0)*64 + lane], C, 0, 0, 0);
                C = __builtin_amdgcn_mfma_f32_32x32x16_f16(ones, ldsb[(NREAL+1)*64 + lane], C, 0, 0, 0);
            }

            #pragma unroll
            for (int q = 0; q < 4; ++q) {
                #pragma unroll
                for (int m = 0; m < 4; ++m) {
                    const int row = v0 + 8*q + 4*g + m;
                    pk_atomic_row(aggH, row < N ? row : -1, o, C[4*q + m]);
                }
            }
        }
    }
}

// ---------------------------------------------------------------------------
// l3_pre: per node v — P[v][k,o] = sum_i relu(f)[i] w2[k,2i+o] (f16),
// Q[v][o] = sum_i relu(f)[i] b2[2i+o], node term -> out (overwrite).
// P row: 36 half2 = 72 f16 = 144 B (33 used: k=0..31 + Q at slot 32).
// ---------------------------------------------------------------------------
__global__ __launch_bounds__(256) void l3_pre(
    const _Float16* __restrict__ fprev,   // agg2: N x 32 f16, pre-relu
    const float* __restrict__ w2,         // (32, 64)
    const float* __restrict__ b2,         // (64)
    const float* __restrict__ root,       // (32, 2)
    const float* __restrict__ bias,       // (2)
    _Float16* __restrict__ P,             // N x 72 f16
    float* __restrict__ out, int N)
{
    int v = blockIdx.x * 256 + threadIdx.x;
    if (v >= N) return;

    float xf[32];
    {
        const half8v* fp = (const half8v*)(fprev + (size_t)v * 32);
        #pragma unroll
        for (int q = 0; q < 4; ++q) {
            half8v u = fp[q];
            #pragma unroll
            for (int j = 0; j < 8; ++j)
                xf[8*q + j] = fmaxf((float)u[j], 0.f);
        }
    }

    union { uint4 u[9]; half2v h[36]; } pb;
    #pragma unroll
    for (int k = 0; k < 32; ++k) {
        const float* wk = w2 + (size_t)k * 64;       // wave-uniform
        float p0 = 0.f, p1 = 0.f;
        #pragma unroll
        for (int i = 0; i < 32; ++i) {
            p0 = fmaf(xf[i], wk[2*i    ], p0);
            p1 = fmaf(xf[i], wk[2*i + 1], p1);
        }
        half2v hp; hp[0] = (_Float16)p0; hp[1] = (_Float16)p1;
        pb.h[k] = hp;
    }
    {
        float q0 = 0.f, q1 = 0.f;
        #pragma unroll
        for (int i = 0; i < 32; ++i) {
            q0 = fmaf(xf[i], b2[2*i    ], q0);
            q1 = fmaf(xf[i], b2[2*i + 1], q1);
        }
        half2v hq; hq[0] = (_Float16)q0; hq[1] = (_Float16)q1;
        pb.h[32] = hq;
        half2v hz; hz[0] = (_Float16)0.f; hz[1] = (_Float16)0.f;
        pb.h[33] = hz; pb.h[34] = hz; pb.h[35] = hz;
    }
    uint4* dp = (uint4*)(P + (size_t)v * 72);
    #pragma unroll
    for (int q = 0; q < 9; ++q) dp[q] = pb.u[q];

    float a0 = bias[0], a1 = bias[1];
    #pragma unroll
    for (int i = 0; i < 32; ++i) {
        a0 = fmaf(xf[i], root[2*i    ], a0);
        a1 = fmaf(xf[i], root[2*i + 1], a1);
    }
    float2 o2; o2.x = a0; o2.y = a1;
    ((float2*)out)[v] = o2;                          // overwrite, pre-atomics
}

// ---------------------------------------------------------------------------
// l3_edge: per edge — h-chain (packed f16) then msg_o = Q + sum_k h_k P[s][k,o];
// 136 B gather + ~200 VALU, f32 accumulation, 2 f32 atomics into out.
// ---------------------------------------------------------------------------
__global__ __launch_bounds__(256) void l3_edge(
    const int*      __restrict__ src,
    const int*      __restrict__ dst,
    const float*    __restrict__ ea,
    const _Float16* __restrict__ w1h,     // layer3 packed (160 f16)
    const _Float16* __restrict__ P,       // N x 72 f16
    float* __restrict__ out, int E)
{
    int e = blockIdx.x * 256 + threadIdx.x;
    if (e >= E) return;

    const int s = src[e], d = dst[e];
    const float4 av = *(const float4*)(ea + 4ll * e);
    half2v eax; eax[0] = (_Float16)av.x; eax[1] = eax[0];
    half2v eay; eay[0] = (_Float16)av.y; eay[1] = eay[0];
    half2v eaz; eaz[0] = (_Float16)av.z; eaz[1] = eaz[0];
    half2v eaw; eaw[0] = (_Float16)av.w; eaw[1] = eaw[0];

    union { uint4 u[9]; half2v h[36]; } pr;
    {
        const uint4* pp = (const uint4*)(P + (size_t)s * 72);
        #pragma unroll
        for (int q = 0; q < 9; ++q) pr.u[q] = pp[q];
    }

    const half2v* w1p = (const half2v*)w1h;
    const half2v* b1p = (const half2v*)(w1h + 128);
    const half2v zero2 = { (_Float16)0.f, (_Float16)0.f };

    float m0 = (float)pr.h[32][0];                   // Q (b2 term)
    float m1 = (float)pr.h[32][1];
    #pragma unroll 4
    for (int t = 0; t < 16; ++t) {                   // k-pair (2t, 2t+1)
        half2v h2 = eax * w1p[t] + b1p[t];
        h2 = eay * w1p[16 + t] + h2;
        h2 = eaz * w1p[32 + t] + h2;
        h2 = eaw * w1p[48 + t] + h2;
        h2 = __builtin_elementwise_max(h2, zero2);
        const float h0 = (float)h2[0], h1 = (float)h2[1];
        m0 = fmaf(h0, (float)pr.h[2*t    ][0], m0);
        m1 = fmaf(h0, (float)pr.h[2*t    ][1], m1);
        m0 = fmaf(h1, (float)pr.h[2*t + 1][0], m0);
        m1 = fmaf(h1, (float)pr.h[2*t + 1][1], m1);
    }
    unsafeAtomicAdd(out + 2ll*d,     m0);
    unsafeAtomicAdd(out + 2ll*d + 1, m1);
}

// ---------------------------------------------------------------------------
extern "C" void kernel_launch(void* const* d_in, const int* in_sizes, int n_in,
                              void* d_out, int out_size, void* d_ws, size_t ws_size,
                              hipStream_t stream)
{
    const float* x  = (const float*)d_in[0];
    const int*   ei = (const int*)d_in[1];
    const float* ea = (const float*)d_in[2];

    const int E = in_sizes[2] / 4;
    const int N = in_sizes[0] / 10;
    const int* src = ei;
    const int* dst = ei + E;

    const float* p[4][6];   // w1, b1, w2, b2, root, bias
    for (int L = 0; L < 4; ++L)
        for (int j = 0; j < 6; ++j)
            p[L][j] = (const float*)d_in[3 + 6 * L + j];

    char* w = (char*)d_ws;
    auto carve = [&](size_t bytes) {
        char* q = w; w += (bytes + 255) & ~(size_t)255; return (void*)q;
    };
    _Float16* xin  = (_Float16*)carve((size_t)N * 8 * 2);
    _Float16* aggz = (_Float16*)carve((size_t)3 * N * 32 * 2);
    _Float16* bswz = (_Float16*)carve((size_t)BSWZ_TOT * 2);
    _Float16* w1hb = (_Float16*)carve((size_t)W1H_TOT * 2);
    _Float16* Pbuf = (_Float16*)carve((size_t)N * 72 * 2);   // 14.4 MB
    _Float16* agg0 = aggz;
    _Float16* agg1 = aggz + (size_t)N * 32;
    _Float16* agg2 = aggz + (size_t)2 * N * 32;
    float* out  = (float*)d_out;

    Prm prm{};
    prm.x = x;
    for (int L = 0; L < 4; ++L) {
        prm.w1[L] = p[L][0]; prm.b1[L] = p[L][1];
        prm.w2[L] = p[L][2]; prm.b2[L] = p[L][3];
        prm.root[L] = p[L][4]; prm.bias[L] = p[L][5];
    }
    prm.xin = xin; prm.bswz = bswz; prm.w1h = w1hb;
    prm.aggz = aggz; prm.outz = out; prm.N = N;

    const int NB8 = (N * 8 + 255) / 256;
    const int NZA = (N * 12 + 255) / 256;
    const int NZO = (N + 255) / 256;

    const int ntileE = (E + 31) / 32;
    const int ntileN = (N + 31) / 32;
    const int ntot   = ntileE + ntileN;
    int NB = (ntot + 15) / 16;                       // 16 waves / block
    if (NB > 512) NB = 512;                          // 2 blocks/CU co-resident

    const int NBN = (N + 255) / 256;
    const int NBE = (E + 255) / 256;

    // 6 dispatches total
    prep<<<452 + NB8 + NZA + NZO + 1, 256, 0, stream>>>(prm, NB8, NZA, NZO);

    edge<8><<<NB, 1024, 0, stream>>>(                // layer 0
        xin, nullptr, src, dst, ea, w1hb + 0 * 160,
        bswz + 0 * 512, agg0, E, N, ntileE, ntot);

    edge<32><<<NB, 1024, 0, stream>>>(               // layer 1
        nullptr, agg0, src, dst, ea, w1hb + 1 * 160,
        bswz + 19 * 512, agg1, E, N, ntileE, ntot);

    edge<32><<<NB, 1024, 0, stream>>>(               // layer 2
        nullptr, agg1, src, dst, ea, w1hb + 2 * 160,
        bswz + 88 * 512, agg2, E, N, ntileE, ntot);

    l3_pre<<<NBN, 256, 0, stream>>>(                 // P + node term -> out
        agg2, p[3][2], p[3][3], p[3][4], p[3][5], Pbuf, out, N);

    l3_edge<<<NBE, 256, 0, stream>>>(                // msg -> out (atomics)
        src, dst, ea, w1hb + 3 * 160, Pbuf, out, E);
}

// Round 22
// 152.393 us; speedup vs baseline: 1.0024x; 1.0024x over previous
//
#include <hip/hip_runtime.h>
#include <hip/hip_fp16.h>

typedef __attribute__((ext_vector_type(2)))  _Float16 half2v;  // 2 f16 = 1 VGPR
typedef __attribute__((ext_vector_type(8)))  _Float16 half8v;  // 8 f16 = 4 VGPR
typedef __attribute__((ext_vector_type(16))) float    f32x16;

// bswz step layout (512 f16 per step), offsets in steps:
//  L0 real [0,17)   L0 self [17,19)
//  L1 real [19,85)  L1 self [85,88)
//  L2 real [88,154) L2 self [154,157)
//  L3 real [157,223) L3 self [223,226)   (L3 steps now unused but kept: prep identical)
static constexpr int BSWZ_STEPS = 226;
static constexpr int BSWZ_TOT   = BSWZ_STEPS * 512;   // 115712 f16
static constexpr int W1H_TOT    = 4 * 160;

struct Prm {
    const float* x;
    const float* w1[4]; const float* b1[4];
    const float* w2[4]; const float* b2[4];
    const float* root[4]; const float* bias[4];
    _Float16* xin;    // N x 8 f16 (x[:,4:10], zero-padded)
    _Float16* bswz;
    _Float16* w1h;    // 640 f16
    _Float16* aggz;   // 3 * N * 32 f16 (agg0|agg1|agg2), zeroed here
    float* outz;      // N x 2 f32 (d_out), zeroed here
    int N;
};

// ---------------------------------------------------------------------------
// prep: identical to R19.
// ---------------------------------------------------------------------------
__global__ __launch_bounds__(256) void prep(Prm p, int NB8, int NZA, int NZO)
{
    int b = blockIdx.x;
    if (b < 452) {                                   // ---- bswz ----
        int i = b * 256 + threadIdx.x;
        int T = i >> 9, t2 = i & 511;
        int j = t2 & 7, l = (t2 >> 3) & 63;
        int g = l >> 5, o = l & 31;
        int layer, cls, t;
        if (T < 17)       { layer = 0; cls = 0; t = T; }
        else if (T < 19)  { layer = 0; cls = 1; t = T - 17; }
        else if (T < 85)  { layer = 1; cls = 0; t = T - 19; }
        else if (T < 88)  { layer = 1; cls = 1; t = T - 85; }
        else if (T < 154) { layer = 2; cls = 0; t = T - 88; }
        else if (T < 157) { layer = 2; cls = 1; t = T - 154; }
        else if (T < 223) { layer = 3; cls = 0; t = T - 157; }
        else              { layer = 3; cls = 1; t = T - 223; }
        const int INP   = (layer == 0) ? 8 : 32;
        const int IN_C  = (layer == 0) ? 6 : 32;
        const int OUT_C = (layer == 3) ? 2 : 32;
        float v = 0.f;
        if (cls == 0) {
            const int S_MAIN = 2 * INP;
            if (t < S_MAIN) {
                int kap = 16 * t + 8 * g + j;
                int k  = (INP == 8) ? (kap >> 3) : (kap >> 5);
                int ii = (INP == 8) ? (kap & 7)  : (kap & 31);
                if (ii < IN_C && o < OUT_C)
                    v = p.w2[layer][(size_t)k * (IN_C * OUT_C) + ii * OUT_C + o];
            } else {
                int ii = 16 * (t - S_MAIN) + 8 * g + j;
                if (ii < IN_C && o < OUT_C)
                    v = p.b2[layer][ii * OUT_C + o];
            }
        } else {
            const int nroot = (layer == 0) ? 1 : 2;
            if (t < nroot) {
                int ii = 16 * t + 8 * g + j;
                if (ii < IN_C && o < OUT_C)
                    v = p.root[layer][ii * OUT_C + o];
            } else {
                if (g == 0 && j == 0 && o < OUT_C)
                    v = p.bias[layer][o];
            }
        }
        p.bswz[i] = (_Float16)v;
    } else if (b < 452 + NB8) {                      // ---- pack xin ----
        int i = (b - 452) * 256 + threadIdx.x;
        if (i < p.N * 8) {
            int v = i >> 3, c = i & 7;
            float val = (c < 6) ? p.x[(size_t)v * 10 + 4 + c] : 0.f;
            p.xin[i] = (_Float16)val;
        }
    } else if (b < 452 + NB8 + NZA) {                // ---- zero agg0..2 ----
        long long i = (long long)(b - 452 - NB8) * 256 + threadIdx.x;
        if (i < (long long)p.N * 12)
            ((uint4*)p.aggz)[i] = uint4{0u, 0u, 0u, 0u};
    } else if (b < 452 + NB8 + NZA + NZO) {          // ---- zero out ----
        int v = (b - 452 - NB8 - NZA) * 256 + threadIdx.x;
        if (v < p.N)
            ((float2*)p.outz)[v] = float2{0.f, 0.f};
    } else {                                         // ---- w1h / b1h ----
        for (int i = threadIdx.x; i < W1H_TOT; i += 256) {
            int layer = i / 160, r = i % 160;
            float v = (r < 128) ? p.w1[layer][r]
                                : p.b1[layer][r - 128];
            p.w1h[i] = (_Float16)v;
        }
    }
}

// gather 32 f16 feats for node s, relu in packed f16
static __device__ __forceinline__ void gather32h(
    const _Float16* __restrict__ fprev, int s, int g, half8v& xh0, half8v& xh1)
{
    const half8v* fp = (const half8v*)(fprev + (size_t)s * 32);
    xh0 = fp[g];
    xh1 = fp[2 + g];
    #pragma unroll
    for (int j = 0; j < 8; ++j) {
        xh0[j] = xh0[j] > (_Float16)0.f ? xh0[j] : (_Float16)0.f;
        xh1[j] = xh1[j] > (_Float16)0.f ? xh1[j] : (_Float16)0.f;
    }
}

static __device__ __forceinline__ half8v splat8(_Float16 h)
{
    half8v r;
    #pragma unroll
    for (int j = 0; j < 8; ++j) r[j] = h;
    return r;
}

// paired pk-f16 atomic: lanes o and o^1 hold the same row, cols o / o^1.
static __device__ __forceinline__ void pk_atomic_row(
    _Float16* __restrict__ aggH, int row, int o, float mine)
{
    float oth = __shfl_xor(mine, 1);
    if ((o & 1) == 0 && row >= 0) {
        __half2 v = __floats2half2_rn(mine, oth);
        unsafeAtomicAdd((__half2*)aggH + (((size_t)row << 5) + o) / 2, v);
    }
}

// ---------------------------------------------------------------------------
// Edge kernel for layers 0-2: identical to R19's edge<INP,32>.
// ---------------------------------------------------------------------------
template<int INP>
__global__ __launch_bounds__(1024, 8) void edge(
    const _Float16* __restrict__ xin,
    const _Float16* __restrict__ fprev,
    const int*      __restrict__ src,
    const int*      __restrict__ dst,
    const float*    __restrict__ ea,
    const _Float16* __restrict__ w1h,
    const _Float16* __restrict__ bAll,
    _Float16* __restrict__ aggH,
    int E, int N, int ntileE, int ntot)
{
    constexpr int NREAL = (INP == 32) ? 66 : 17;
    constexpr int NSELF = (INP == 32) ? 3  : 2;
    constexpr int NSTEP = NREAL + NSELF;

    __shared__ half8v ldsb[NSTEP * 64];
    {
        const half8v* bp = (const half8v*)bAll;
        for (int i = threadIdx.x; i < NSTEP * 64; i += 1024)
            ldsb[i] = bp[i];
    }
    __syncthreads();

    const int lane = threadIdx.x & 63;
    const int g = lane >> 5, o = lane & 31;
    const int lrow = lane & 31;
    const int wv = (blockIdx.x * 1024 + threadIdx.x) >> 6;
    const int nw = gridDim.x * 16;

    const half2v* w1p = (const half2v*)w1h;
    const half2v* b1p = (const half2v*)(w1h + 128);
    const half2v zero2 = { (_Float16)0.f, (_Float16)0.f };

    half8v ones;
    #pragma unroll
    for (int j = 0; j < 8; ++j) ones[j] = (_Float16)0.f;
    ones[0] = (_Float16)1.f;

    for (int tile = wv; tile < ntot; tile += nw) {
        f32x16 C;
        #pragma unroll
        for (int i = 0; i < 16; ++i) C[i] = 0.f;

        if (tile < ntileE) {
            const int e0 = tile * 32;
            const int er = e0 + lrow;
            const int ec = er < E ? er : (E - 1);
            const int s  = src[ec];
            const float4 av = *(const float4*)(ea + 4ll * ec);
            half2v eax; eax[0] = (_Float16)av.x; eax[1] = eax[0];
            half2v eay; eay[0] = (_Float16)av.y; eay[1] = eay[0];
            half2v eaz; eaz[0] = (_Float16)av.z; eaz[1] = eaz[0];
            half2v eaw; eaw[0] = (_Float16)av.w; eaw[1] = eaw[0];

            half8v xh0, xh1;
            if constexpr (INP == 32) gather32h(fprev, s, g, xh0, xh1);
            else                     xh0 = *(const half8v*)(xin + (size_t)s * 8);

            if constexpr (INP == 32) {
                #pragma unroll 2
                for (int t = 0; t < 16; ++t) {
                    half2v h2 = eax * w1p[t] + b1p[t];
                    h2 = eay * w1p[16 + t] + h2;
                    h2 = eaz * w1p[32 + t] + h2;
                    h2 = eaw * w1p[48 + t] + h2;
                    h2 = __builtin_elementwise_max(h2, zero2);
                    half8v hsl = splat8(h2[0]);
                    half8v hsh = splat8(h2[1]);
                    half8v bf0 = ldsb[(4*t    ) * 64 + lane];
                    half8v bf1 = ldsb[(4*t + 1) * 64 + lane];
                    half8v bf2 = ldsb[(4*t + 2) * 64 + lane];
                    half8v bf3 = ldsb[(4*t + 3) * 64 + lane];
                    C = __builtin_amdgcn_mfma_f32_32x32x16_f16(hsl * xh0, bf0, C, 0, 0, 0);
                    C = __builtin_amdgcn_mfma_f32_32x32x16_f16(hsl * xh1, bf1, C, 0, 0, 0);
                    C = __builtin_amdgcn_mfma_f32_32x32x16_f16(hsh * xh0, bf2, C, 0, 0, 0);
                    C = __builtin_amdgcn_mfma_f32_32x32x16_f16(hsh * xh1, bf3, C, 0, 0, 0);
                }
                C = __builtin_amdgcn_mfma_f32_32x32x16_f16(xh0, ldsb[64*64 + lane], C, 0, 0, 0);
                C = __builtin_amdgcn_mfma_f32_32x32x16_f16(xh1, ldsb[65*64 + lane], C, 0, 0, 0);
            } else {
                #pragma unroll 4
                for (int t = 0; t < 16; ++t) {
                    half2v h2 = eax * w1p[t] + b1p[t];
                    h2 = eay * w1p[16 + t] + h2;
                    h2 = eaz * w1p[32 + t] + h2;
                    h2 = eaw * w1p[48 + t] + h2;
                    h2 = __builtin_elementwise_max(h2, zero2);
                    half8v hs = splat8(g ? h2[1] : h2[0]);
                    half8v bf = ldsb[t * 64 + lane];
                    C = __builtin_amdgcn_mfma_f32_32x32x16_f16(hs * xh0, bf, C, 0, 0, 0);
                }
                half8v zz;
                #pragma unroll
                for (int j = 0; j < 8; ++j) zz[j] = (_Float16)0.f;
                half8v a = (g == 0) ? xh0 : zz;
                C = __builtin_amdgcn_mfma_f32_32x32x16_f16(a, ldsb[16*64 + lane], C, 0, 0, 0);
            }

            #pragma unroll
            for (int q = 0; q < 4; ++q) {
                const int eb = e0 + 8 * q + 4 * g;
                int rows[4];
                if (eb + 3 < E) {
                    const int4 dd = *(const int4*)(dst + eb);
                    rows[0] = dd.x; rows[1] = dd.y; rows[2] = dd.z; rows[3] = dd.w;
                } else {
                    #pragma unroll
                    for (int m = 0; m < 4; ++m)
                        rows[m] = (eb + m < E) ? dst[eb + m] : -1;
                }
                #pragma unroll
                for (int m = 0; m < 4; ++m)
                    pk_atomic_row(aggH, rows[m], o, C[4*q + m]);
            }
        } else {
            const int v0 = (tile - ntileE) * 32;
            const int vr = v0 + lrow;
            const int vc = vr < N ? vr : (N - 1);

            if constexpr (INP == 32) {
                half8v xh0, xh1;
                gather32h(fprev, vc, g, xh0, xh1);
                C = __builtin_amdgcn_mfma_f32_32x32x16_f16(xh0,  ldsb[(NREAL+0)*64 + lane], C, 0, 0, 0);
                C = __builtin_amdgcn_mfma_f32_32x32x16_f16(xh1,  ldsb[(NREAL+1)*64 + lane], C, 0, 0, 0);
                C = __builtin_amdgcn_mfma_f32_32x32x16_f16(ones, ldsb[(NREAL+2)*64 + lane], C, 0, 0, 0);
            } else {
                half8v xh0 = *(const half8v*)(xin + (size_t)vc * 8);
                C = __builtin_amdgcn_mfma_f32_32x32x16_f16(xh0,  ldsb[(NREAL+0)*64 + lane], C, 0, 0, 0);
                C = __builtin_amdgcn_mfma_f32_32x32x16_f16(ones, ldsb[(NREAL+1)*64 + lane], C, 0, 0, 0);
            }

            #pragma unroll
            for (int q = 0; q < 4; ++q) {
                #pragma unroll
                for (int m = 0; m < 4; ++m) {
                    const int row = v0 + 8*q + 4*g + m;
                    pk_atomic_row(aggH, row < N ? row : -1, o, C[4*q + m]);
                }
            }
        }
    }
}

// ---------------------------------------------------------------------------
// l3_pre: per node v — P[v][k,o] = sum_i relu(f)[i] w2[k,2i+o] (f16),
// Q[v][o] = sum_i relu(f)[i] b2[2i+o], node term -> out (overwrite).
// P row: 36 half2 = 72 f16 = 144 B (33 used: k=0..31 + Q at slot 32).
// ---------------------------------------------------------------------------
__global__ __launch_bounds__(256) void l3_pre(
    const _Float16* __restrict__ fprev,   // agg2: N x 32 f16, pre-relu
    const float* __restrict__ w2,         // (32, 64)
    const float* __restrict__ b2,         // (64)
    const float* __restrict__ root,       // (32, 2)
    const float* __restrict__ bias,       // (2)
    _Float16* __restrict__ P,             // N x 72 f16
    float* __restrict__ out, int N)
{
    int v = blockIdx.x * 256 + threadIdx.x;
    if (v >= N) return;

    float xf[32];
    {
        const half8v* fp = (const half8v*)(fprev + (size_t)v * 32);
        #pragma unroll
        for (int q = 0; q < 4; ++q) {
            half8v u = fp[q];
            #pragma unroll
            for (int j = 0; j < 8; ++j)
                xf[8*q + j] = fmaxf((float)u[j], 0.f);
        }
    }

    union { uint4 u[9]; half2v h[36]; } pb;
    #pragma unroll
    for (int k = 0; k < 32; ++k) {
        const float* wk = w2 + (size_t)k * 64;       // wave-uniform
        float p0 = 0.f, p1 = 0.f;
        #pragma unroll
        for (int i = 0; i < 32; ++i) {
            p0 = fmaf(xf[i], wk[2*i    ], p0);
            p1 = fmaf(xf[i], wk[2*i + 1], p1);
        }
        half2v hp; hp[0] = (_Float16)p0; hp[1] = (_Float16)p1;
        pb.h[k] = hp;
    }
    {
        float q0 = 0.f, q1 = 0.f;
        #pragma unroll
        for (int i = 0; i < 32; ++i) {
            q0 = fmaf(xf[i], b2[2*i    ], q0);
            q1 = fmaf(xf[i], b2[2*i + 1], q1);
        }
        half2v hq; hq[0] = (_Float16)q0; hq[1] = (_Float16)q1;
        pb.h[32] = hq;
        half2v hz; hz[0] = (_Float16)0.f; hz[1] = (_Float16)0.f;
        pb.h[33] = hz; pb.h[34] = hz; pb.h[35] = hz;
    }
    uint4* dp = (uint4*)(P + (size_t)v * 72);
    #pragma unroll
    for (int q = 0; q < 9; ++q) dp[q] = pb.u[q];

    float a0 = bias[0], a1 = bias[1];
    #pragma unroll
    for (int i = 0; i < 32; ++i) {
        a0 = fmaf(xf[i], root[2*i    ], a0);
        a1 = fmaf(xf[i], root[2*i + 1], a1);
    }
    float2 o2; o2.x = a0; o2.y = a1;
    ((float2*)out)[v] = o2;                          // overwrite, pre-atomics
}

// ---------------------------------------------------------------------------
// l3_edge: per edge — h-chain (packed f16) then msg_o = Q + sum_k h_k P[s][k,o];
// 136 B gather + ~200 VALU, f32 accumulation, 2 f32 atomics into out.
// ---------------------------------------------------------------------------
__global__ __launch_bounds__(256) void l3_edge(
    const int*      __restrict__ src,
    const int*      __restrict__ dst,
    const float*    __restrict__ ea,
    const _Float16* __restrict__ w1h,     // layer3 packed (160 f16)
    const _Float16* __restrict__ P,       // N x 72 f16
    float* __restrict__ out, int E)
{
    int e = blockIdx.x * 256 + threadIdx.x;
    if (e >= E) return;

    const int s = src[e], d = dst[e];
    const float4 av = *(const float4*)(ea + 4ll * e);
    half2v eax; eax[0] = (_Float16)av.x; eax[1] = eax[0];
    half2v eay; eay[0] = (_Float16)av.y; eay[1] = eay[0];
    half2v eaz; eaz[0] = (_Float16)av.z; eaz[1] = eaz[0];
    half2v eaw; eaw[0] = (_Float16)av.w; eaw[1] = eaw[0];

    union { uint4 u[9]; half2v h[36]; } pr;
    {
        const uint4* pp = (const uint4*)(P + (size_t)s * 72);
        #pragma unroll
        for (int q = 0; q < 9; ++q) pr.u[q] = pp[q];
    }

    const half2v* w1p = (const half2v*)w1h;
    const half2v* b1p = (const half2v*)(w1h + 128);
    const half2v zero2 = { (_Float16)0.f, (_Float16)0.f };

    float m0 = (float)pr.h[32][0];                   // Q (b2 term)
    float m1 = (float)pr.h[32][1];
    #pragma unroll 4
    for (int t = 0; t < 16; ++t) {                   // k-pair (2t, 2t+1)
        half2v h2 = eax * w1p[t] + b1p[t];
        h2 = eay * w1p[16 + t] + h2;
        h2 = eaz * w1p[32 + t] + h2;
        h2 = eaw * w1p[48 + t] + h2;
        h2 = __builtin_elementwise_max(h2, zero2);
        const float h0 = (float)h2[0], h1 = (float)h2[1];
        m0 = fmaf(h0, (float)pr.h[2*t    ][0], m0);
        m1 = fmaf(h0, (float)pr.h[2*t    ][1], m1);
        m0 = fmaf(h1, (float)pr.h[2*t + 1][0], m0);
        m1 = fmaf(h1, (float)pr.h[2*t + 1][1], m1);
    }
    unsafeAtomicAdd(out + 2ll*d,     m0);
    unsafeAtomicAdd(out + 2ll*d + 1, m1);
}

// ---------------------------------------------------------------------------
extern "C" void kernel_launch(void* const* d_in, const int* in_sizes, int n_in,
                              void* d_out, int out_size, void* d_ws, size_t ws_size,
                              hipStream_t stream)
{
    const float* x  = (const float*)d_in[0];
    const int*   ei = (const int*)d_in[1];
    const float* ea = (const float*)d_in[2];

    const int E = in_sizes[2] / 4;
    const int N = in_sizes[0] / 10;
    const int* src = ei;
    const int* dst = ei + E;

    const float* p[4][6];   // w1, b1, w2, b2, root, bias
    for (int L = 0; L < 4; ++L)
        for (int j = 0; j < 6; ++j)
            p[L][j] = (const float*)d_in[3 + 6 * L + j];

    char* w = (char*)d_ws;
    auto carve = [&](size_t bytes) {
        char* q = w; w += (bytes + 255) & ~(size_t)255; return (void*)q;
    };
    _Float16* xin  = (_Float16*)carve((size_t)N * 8 * 2);
    _Float16* aggz = (_Float16*)carve((size_t)3 * N * 32 * 2);
    _Float16* bswz = (_Float16*)carve((size_t)BSWZ_TOT * 2);
    _Float16* w1hb = (_Float16*)carve((size_t)W1H_TOT * 2);
    _Float16* Pbuf = (_Float16*)carve((size_t)N * 72 * 2);   // 14.4 MB
    _Float16* agg0 = aggz;
    _Float16* agg1 = aggz + (size_t)N * 32;
    _Float16* agg2 = aggz + (size_t)2 * N * 32;
    float* out  = (float*)d_out;

    Prm prm{};
    prm.x = x;
    for (int L = 0; L < 4; ++L) {
        prm.w1[L] = p[L][0]; prm.b1[L] = p[L][1];
        prm.w2[L] = p[L][2]; prm.b2[L] = p[L][3];
        prm.root[L] = p[L][4]; prm.bias[L] = p[L][5];
    }
    prm.xin = xin; prm.bswz = bswz; prm.w1h = w1hb;
    prm.aggz = aggz; prm.outz = out; prm.N = N;

    const int NB8 = (N * 8 + 255) / 256;
    const int NZA = (N * 12 + 255) / 256;
    const int NZO = (N + 255) / 256;

    const int ntileE = (E + 31) / 32;
    const int ntileN = (N + 31) / 32;
    const int ntot   = ntileE + ntileN;
    int NB = (ntot + 15) / 16;                       // 16 waves / block
    if (NB > 512) NB = 512;                          // 2 blocks/CU co-resident

    const int NBN = (N + 255) / 256;
    const int NBE = (E + 255) / 256;

    // 6 dispatches total
    prep<<<452 + NB8 + NZA + NZO + 1, 256, 0, stream>>>(prm, NB8, NZA, NZO);

    edge<8><<<NB, 1024, 0, stream>>>(                // layer 0
        xin, nullptr, src, dst, ea, w1hb + 0 * 160,
        bswz + 0 * 512, agg0, E, N, ntileE, ntot);

    edge<32><<<NB, 1024, 0, stream>>>(               // layer 1
        nullptr, agg0, src, dst, ea, w1hb + 1 * 160,
        bswz + 19 * 512, agg1, E, N, ntileE, ntot);

    edge<32><<<NB, 1024, 0, stream>>>(               // layer 2
        nullptr, agg1, src, dst, ea, w1hb + 2 * 160,
        bswz + 88 * 512, agg2, E, N, ntileE, ntot);

    l3_pre<<<NBN, 256, 0, stream>>>(                 // P + node term -> out
        agg2, p[3][2], p[3][3], p[3][4], p[3][5], Pbuf, out, N);

    l3_edge<<<NBE, 256, 0, stream>>>(                // msg -> out (atomics)
        src, dst, ea, w1hb + 3 * 160, Pbuf, out, E);
}

// Round 23
// 111.647 us; speedup vs baseline: 1.3682x; 1.3649x over previous
//
#include <hip/hip_runtime.h>
#include <hip/hip_fp16.h>

typedef __attribute__((ext_vector_type(2)))  _Float16 half2v;  // 2 f16 = 1 VGPR
typedef __attribute__((ext_vector_type(8)))  _Float16 half8v;  // 8 f16 = 4 VGPR
typedef __attribute__((ext_vector_type(16))) float    f32x16;

// bswz step layout (512 f16 per step), offsets in steps:
//  L0 real [0,17)   L0 self [17,19)
//  L1 real [19,85)  L1 self [85,88)
//  L2 real [88,154) L2 self [154,157)
//  L3 real [157,223) L3 self [223,226)
// then 4 x 160 f16 of packed w1h/b1h per layer.
static constexpr int BSWZ_STEPS = 226;
static constexpr int BSWZ_TOT   = BSWZ_STEPS * 512;   // 115712 f16
static constexpr int W1H_TOT    = 4 * 160;            // w1h[4][32] + b1h[32] per layer

struct Prm {
    const float* x;
    const float* w1[4]; const float* b1[4];
    const float* w2[4]; const float* b2[4];
    const float* root[4]; const float* bias[4];
    _Float16* xin;    // N x 8 f16 (x[:,4:10], zero-padded)
    _Float16* bswz;
    _Float16* w1h;    // 640 f16: per layer {w1 k-pairs (4x16 half2), b1 (16 half2)}
    _Float16* aggz;   // 3 * N * 32 f16 (agg0|agg1|agg2), zeroed here
    float* outz;      // N x 2 f32 (d_out), zeroed here
    int N;
};

// ---------------------------------------------------------------------------
// prep: [0,452) build bswz ; [452,452+NB8) pack xin ;
//       [.., +NZA) zero agg0..2 ; [.., +NZO) zero out ; last block: w1h/b1h
//       (grid-stride over all 640 elements).
// ---------------------------------------------------------------------------
__global__ __launch_bounds__(256) void prep(Prm p, int NB8, int NZA, int NZO)
{
    int b = blockIdx.x;
    if (b < 452) {                                   // ---- bswz ----
        int i = b * 256 + threadIdx.x;               // < 115712 exactly
        int T = i >> 9, t2 = i & 511;
        int j = t2 & 7, l = (t2 >> 3) & 63;
        int g = l >> 5, o = l & 31;
        int layer, cls, t;                           // cls: 0 real, 1 self
        if (T < 17)       { layer = 0; cls = 0; t = T; }
        else if (T < 19)  { layer = 0; cls = 1; t = T - 17; }
        else if (T < 85)  { layer = 1; cls = 0; t = T - 19; }
        else if (T < 88)  { layer = 1; cls = 1; t = T - 85; }
        else if (T < 154) { layer = 2; cls = 0; t = T - 88; }
        else if (T < 157) { layer = 2; cls = 1; t = T - 154; }
        else if (T < 223) { layer = 3; cls = 0; t = T - 157; }
        else              { layer = 3; cls = 1; t = T - 223; }
        const int INP   = (layer == 0) ? 8 : 32;
        const int IN_C  = (layer == 0) ? 6 : 32;
        const int OUT_C = (layer == 3) ? 2 : 32;
        float v = 0.f;
        if (cls == 0) {
            const int S_MAIN = 2 * INP;
            if (t < S_MAIN) {
                int kap = 16 * t + 8 * g + j;
                int k  = (INP == 8) ? (kap >> 3) : (kap >> 5);
                int ii = (INP == 8) ? (kap & 7)  : (kap & 31);
                if (ii < IN_C && o < OUT_C)
                    v = p.w2[layer][(size_t)k * (IN_C * OUT_C) + ii * OUT_C + o];
            } else {
                int ii = 16 * (t - S_MAIN) + 8 * g + j;
                if (ii < IN_C && o < OUT_C)
                    v = p.b2[layer][ii * OUT_C + o];
            }
        } else {
            const int nroot = (layer == 0) ? 1 : 2;
            if (t < nroot) {
                int ii = 16 * t + 8 * g + j;
                if (ii < IN_C && o < OUT_C)
                    v = p.root[layer][ii * OUT_C + o];
            } else {
                if (g == 0 && j == 0 && o < OUT_C)
                    v = p.bias[layer][o];
            }
        }
        p.bswz[i] = (_Float16)v;
    } else if (b < 452 + NB8) {                      // ---- pack xin ----
        int i = (b - 452) * 256 + threadIdx.x;
        if (i < p.N * 8) {
            int v = i >> 3, c = i & 7;
            float val = (c < 6) ? p.x[(size_t)v * 10 + 4 + c] : 0.f;
            p.xin[i] = (_Float16)val;
        }
    } else if (b < 452 + NB8 + NZA) {                // ---- zero agg0..2 ----
        long long i = (long long)(b - 452 - NB8) * 256 + threadIdx.x;
        if (i < (long long)p.N * 12)                 // 3*N*32*2B / 16B
            ((uint4*)p.aggz)[i] = uint4{0u, 0u, 0u, 0u};
    } else if (b < 452 + NB8 + NZA + NZO) {          // ---- zero out ----
        int v = (b - 452 - NB8 - NZA) * 256 + threadIdx.x;
        if (v < p.N)
            ((float2*)p.outz)[v] = float2{0.f, 0.f};
    } else {                                         // ---- w1h / b1h ----
        for (int i = threadIdx.x; i < W1H_TOT; i += 256) {
            int layer = i / 160, r = i % 160;
            float v = (r < 128) ? p.w1[layer][r]     // w1 row-major (4,32)
                                : p.b1[layer][r - 128];
            p.w1h[i] = (_Float16)v;
        }
    }
}

// gather 32 f16 feats for node s, relu in packed f16
static __device__ __forceinline__ void gather32h(
    const _Float16* __restrict__ fprev, int s, int g, half8v& xh0, half8v& xh1)
{
    const half8v* fp = (const half8v*)(fprev + (size_t)s * 32);
    xh0 = fp[g];
    xh1 = fp[2 + g];
    #pragma unroll
    for (int j = 0; j < 8; ++j) {
        xh0[j] = xh0[j] > (_Float16)0.f ? xh0[j] : (_Float16)0.f;
        xh1[j] = xh1[j] > (_Float16)0.f ? xh1[j] : (_Float16)0.f;
    }
}

// splat one f16 value into all 8 lanes of a half8v
static __device__ __forceinline__ half8v splat8(_Float16 h)
{
    half8v r;
    #pragma unroll
    for (int j = 0; j < 8; ++j) r[j] = h;
    return r;
}

// paired pk-f16 atomic: lanes o and o^1 hold the same row, cols o / o^1.
static __device__ __forceinline__ void pk_atomic_row(
    _Float16* __restrict__ aggH, int row, int o, float mine)
{
    float oth = __shfl_xor(mine, 1);
    if ((o & 1) == 0 && row >= 0) {
        __half2 v = __floats2half2_rn(mine, oth);
        unsafeAtomicAdd((__half2*)aggH + (((size_t)row << 5) + o) / 2, v);
    }
}

// ---------------------------------------------------------------------------
// Edge kernel (1024-thread blocks, 32 waves/CU, LDS-staged B, pk-f16 atomics)
// with PACKED f16 h-chain: h2 = max(fma2 x4) — v_pk_fma_f16/v_pk_max_f16,
// 5 packed ops per TWO k.
// C layout: col = lane&31, row = (r&3)+8*(r>>2)+4*(lane>>5).
// ---------------------------------------------------------------------------
template<int INP, int OUT_C>
__global__ __launch_bounds__(1024, 8) void edge(
    const _Float16* __restrict__ xin,     // layer0 features (N x 8)
    const _Float16* __restrict__ fprev,   // mid features (N x 32 f16, pre-relu)
    const int*      __restrict__ src,
    const int*      __restrict__ dst,
    const float*    __restrict__ ea,
    const _Float16* __restrict__ w1h,     // 160 f16: w1 pairs (4x16 half2v) + b1 (16 half2v)
    const _Float16* __restrict__ bAll,    // real || self fragments, contiguous
    _Float16* __restrict__ aggH,          // N x 32 f16 (OUT_C==32)
    float*    __restrict__ aggF,          // N x 2 f32  (OUT_C==2)
    int E, int N, int ntileE, int ntot)
{
    constexpr int NREAL = (INP == 32) ? 66 : 17;
    constexpr int NSELF = (INP == 32) ? 3  : 2;
    constexpr int NSTEP = NREAL + NSELF;

    __shared__ half8v ldsb[NSTEP * 64];
    {
        const half8v* bp = (const half8v*)bAll;
        for (int i = threadIdx.x; i < NSTEP * 64; i += 1024)
            ldsb[i] = bp[i];
    }
    __syncthreads();

    const int lane = threadIdx.x & 63;
    const int g = lane >> 5, o = lane & 31;
    const int lrow = lane & 31;
    const int wv = (blockIdx.x * 1024 + threadIdx.x) >> 6;
    const int nw = gridDim.x * 16;

    const half2v* w1p = (const half2v*)w1h;          // row*16 + t
    const half2v* b1p = (const half2v*)(w1h + 128);
    const half2v zero2 = { (_Float16)0.f, (_Float16)0.f };

    half8v ones;
    #pragma unroll
    for (int j = 0; j < 8; ++j) ones[j] = (_Float16)0.f;
    ones[0] = (_Float16)1.f;

    for (int tile = wv; tile < ntot; tile += nw) {
        f32x16 C;
        #pragma unroll
        for (int i = 0; i < 16; ++i) C[i] = 0.f;

        if (tile < ntileE) {
            // ================= real edges =================
            const int e0 = tile * 32;
            const int er = e0 + lrow;
            const int ec = er < E ? er : (E - 1);
            const int s  = src[ec];
            const float4 av = *(const float4*)(ea + 4ll * ec);
            half2v eax; eax[0] = (_Float16)av.x; eax[1] = eax[0];
            half2v eay; eay[0] = (_Float16)av.y; eay[1] = eay[0];
            half2v eaz; eaz[0] = (_Float16)av.z; eaz[1] = eaz[0];
            half2v eaw; eaw[0] = (_Float16)av.w; eaw[1] = eaw[0];

            half8v xh0, xh1;
            if constexpr (INP == 32) gather32h(fprev, s, g, xh0, xh1);
            else                     xh0 = *(const half8v*)(xin + (size_t)s * 8);

            if constexpr (INP == 32) {
                #pragma unroll 2
                for (int t = 0; t < 16; ++t) {       // k-pair (2t, 2t+1)
                    half2v h2 = eax * w1p[t] + b1p[t];        // v_pk_fma_f16
                    h2 = eay * w1p[16 + t] + h2;
                    h2 = eaz * w1p[32 + t] + h2;
                    h2 = eaw * w1p[48 + t] + h2;
                    h2 = __builtin_elementwise_max(h2, zero2); // v_pk_max_f16
                    half8v hsl = splat8(h2[0]);
                    half8v hsh = splat8(h2[1]);
                    half8v bf0 = ldsb[(4*t    ) * 64 + lane];
                    half8v bf1 = ldsb[(4*t + 1) * 64 + lane];
                    half8v bf2 = ldsb[(4*t + 2) * 64 + lane];
                    half8v bf3 = ldsb[(4*t + 3) * 64 + lane];
                    C = __builtin_amdgcn_mfma_f32_32x32x16_f16(hsl * xh0, bf0, C, 0, 0, 0);
                    C = __builtin_amdgcn_mfma_f32_32x32x16_f16(hsl * xh1, bf1, C, 0, 0, 0);
                    C = __builtin_amdgcn_mfma_f32_32x32x16_f16(hsh * xh0, bf2, C, 0, 0, 0);
                    C = __builtin_amdgcn_mfma_f32_32x32x16_f16(hsh * xh1, bf3, C, 0, 0, 0);
                }
                C = __builtin_amdgcn_mfma_f32_32x32x16_f16(xh0, ldsb[64*64 + lane], C, 0, 0, 0);
                C = __builtin_amdgcn_mfma_f32_32x32x16_f16(xh1, ldsb[65*64 + lane], C, 0, 0, 0);
            } else {
                #pragma unroll 4
                for (int t = 0; t < 16; ++t) {       // k = 2t + g (lane-dep)
                    half2v h2 = eax * w1p[t] + b1p[t];
                    h2 = eay * w1p[16 + t] + h2;
                    h2 = eaz * w1p[32 + t] + h2;
                    h2 = eaw * w1p[48 + t] + h2;
                    h2 = __builtin_elementwise_max(h2, zero2);
                    half8v hs = splat8(g ? h2[1] : h2[0]);
                    half8v bf = ldsb[t * 64 + lane];
                    C = __builtin_amdgcn_mfma_f32_32x32x16_f16(hs * xh0, bf, C, 0, 0, 0);
                }
                half8v zz;
                #pragma unroll
                for (int j = 0; j < 8; ++j) zz[j] = (_Float16)0.f;
                half8v a = (g == 0) ? xh0 : zz;      // b2 tail
                C = __builtin_amdgcn_mfma_f32_32x32x16_f16(a, ldsb[16*64 + lane], C, 0, 0, 0);
            }

            // epilogue: reg 4q+m -> edge row e0+8q+4g+m, col o
            if constexpr (OUT_C == 32) {
                #pragma unroll
                for (int q = 0; q < 4; ++q) {
                    const int eb = e0 + 8 * q + 4 * g;
                    int rows[4];
                    if (eb + 3 < E) {
                        const int4 dd = *(const int4*)(dst + eb);
                        rows[0] = dd.x; rows[1] = dd.y; rows[2] = dd.z; rows[3] = dd.w;
                    } else {
                        #pragma unroll
                        for (int m = 0; m < 4; ++m)
                            rows[m] = (eb + m < E) ? dst[eb + m] : -1;
                    }
                    #pragma unroll
                    for (int m = 0; m < 4; ++m)
                        pk_atomic_row(aggH, rows[m], o, C[4*q + m]);
                }
            } else {
                if (o < OUT_C) {
                    #pragma unroll
                    for (int q = 0; q < 4; ++q) {
                        const int eb = e0 + 8 * q + 4 * g;
                        #pragma unroll
                        for (int m = 0; m < 4; ++m)
                            if (eb + m < E)
                                unsafeAtomicAdd(aggF + (size_t)dst[eb + m] * OUT_C + o,
                                                C[4*q + m]);
                    }
                }
            }
        } else {
            // ================= self edges (node term) =================
            const int v0 = (tile - ntileE) * 32;
            const int vr = v0 + lrow;
            const int vc = vr < N ? vr : (N - 1);

            if constexpr (INP == 32) {
                half8v xh0, xh1;
                gather32h(fprev, vc, g, xh0, xh1);
                C = __builtin_amdgcn_mfma_f32_32x32x16_f16(xh0,  ldsb[(NREAL+0)*64 + lane], C, 0, 0, 0);
                C = __builtin_amdgcn_mfma_f32_32x32x16_f16(xh1,  ldsb[(NREAL+1)*64 + lane], C, 0, 0, 0);
                C = __builtin_amdgcn_mfma_f32_32x32x16_f16(ones, ldsb[(NREAL+2)*64 + lane], C, 0, 0, 0);
            } else {
                half8v xh0 = *(const half8v*)(xin + (size_t)vc * 8);
                C = __builtin_amdgcn_mfma_f32_32x32x16_f16(xh0,  ldsb[(NREAL+0)*64 + lane], C, 0, 0, 0);
                C = __builtin_amdgcn_mfma_f32_32x32x16_f16(ones, ldsb[(NREAL+1)*64 + lane], C, 0, 0, 0);
            }

            if constexpr (OUT_C == 32) {
                #pragma unroll
                for (int q = 0; q < 4; ++q) {
                    #pragma unroll
                    for (int m = 0; m < 4; ++m) {
                        const int row = v0 + 8*q + 4*g + m;
                        pk_atomic_row(aggH, row < N ? row : -1, o, C[4*q + m]);
                    }
                }
            } else {
                if (o < OUT_C) {
                    #pragma unroll
                    for (int q = 0; q < 4; ++q) {
                        #pragma unroll
                        for (int m = 0; m < 4; ++m) {
                            const int row = v0 + 8*q + 4*g + m;
                            if (row < N)
                                unsafeAtomicAdd(aggF + (size_t)row * OUT_C + o, C[4*q + m]);
                        }
                    }
                }
            }
        }
    }
}

// ---------------------------------------------------------------------------
extern "C" void kernel_launch(void* const* d_in, const int* in_sizes, int n_in,
                              void* d_out, int out_size, void* d_ws, size_t ws_size,
                              hipStream_t stream)
{
    const float* x  = (const float*)d_in[0];
    const int*   ei = (const int*)d_in[1];
    const float* ea = (const float*)d_in[2];

    const int E = in_sizes[2] / 4;
    const int N = in_sizes[0] / 10;
    const int* src = ei;
    const int* dst = ei + E;

    const float* p[4][6];   // w1, b1, w2, b2, root, bias
    for (int L = 0; L < 4; ++L)
        for (int j = 0; j < 6; ++j)
            p[L][j] = (const float*)d_in[3 + 6 * L + j];

    char* w = (char*)d_ws;
    auto carve = [&](size_t bytes) {
        char* q = w; w += (bytes + 255) & ~(size_t)255; return (void*)q;
    };
    _Float16* xin  = (_Float16*)carve((size_t)N * 8 * 2);
    _Float16* aggz = (_Float16*)carve((size_t)3 * N * 32 * 2); // agg0|agg1|agg2 f16
    _Float16* bswz = (_Float16*)carve((size_t)BSWZ_TOT * 2);
    _Float16* w1hb = (_Float16*)carve((size_t)W1H_TOT * 2);
    _Float16* agg0 = aggz;
    _Float16* agg1 = aggz + (size_t)N * 32;
    _Float16* agg2 = aggz + (size_t)2 * N * 32;
    float* out  = (float*)d_out;

    Prm prm{};
    prm.x = x;
    for (int L = 0; L < 4; ++L) {
        prm.w1[L] = p[L][0]; prm.b1[L] = p[L][1];
        prm.w2[L] = p[L][2]; prm.b2[L] = p[L][3];
        prm.root[L] = p[L][4]; prm.bias[L] = p[L][5];
    }
    prm.xin = xin; prm.bswz = bswz; prm.w1h = w1hb;
    prm.aggz = aggz; prm.outz = out; prm.N = N;

    const int NB8 = (N * 8 + 255) / 256;
    const int NZA = (N * 12 + 255) / 256;            // 3*N*32*2B / 16B uint4
    const int NZO = (N + 255) / 256;                 // N float2

    const int ntileE = (E + 31) / 32;
    const int ntileN = (N + 31) / 32;
    const int ntot   = ntileE + ntileN;
    int NB = (ntot + 15) / 16;                       // 16 waves / block
    if (NB > 512) NB = 512;                          // 2 blocks/CU co-resident

    // 5 dispatches total
    prep<<<452 + NB8 + NZA + NZO + 1, 256, 0, stream>>>(prm, NB8, NZA, NZO);

    edge<8, 32><<<NB, 1024, 0, stream>>>(            // layer 0
        xin, nullptr, src, dst, ea, w1hb + 0 * 160,
        bswz + 0 * 512, agg0, nullptr, E, N, ntileE, ntot);

    edge<32, 32><<<NB, 1024, 0, stream>>>(           // layer 1
        nullptr, agg0, src, dst, ea, w1hb + 1 * 160,
        bswz + 19 * 512, agg1, nullptr, E, N, ntileE, ntot);

    edge<32, 32><<<NB, 1024, 0, stream>>>(           // layer 2
        nullptr, agg1, src, dst, ea, w1hb + 2 * 160,
        bswz + 88 * 512, agg2, nullptr, E, N, ntileE, ntot);

    edge<32, 2><<<NB, 1024, 0, stream>>>(            // layer 3 -> d_out
        nullptr, agg2, src, dst, ea, w1hb + 3 * 160,
        bswz + 157 * 512, nullptr, out, E, N, ntileE, ntot);
}